// Round 10
// baseline (172.313 us; speedup 1.0000x reference)
//
#include <hip/hip_runtime.h>
#include <stdint.h>

#define B_  2
#define S_  2048
#define D_  1024
#define H_  16
#define HD_ 64
#define TOK (B_*S_)   // 4096

typedef __bf16 bf16x8 __attribute__((ext_vector_type(8)));
typedef __bf16 bf16x4 __attribute__((ext_vector_type(4)));
typedef float  f32x4  __attribute__((ext_vector_type(4)));

static_assert(sizeof(bf16x8) == 16, "bf16x8 must be 16B");
static_assert(sizeof(bf16x4) == 8,  "bf16x4 must be 8B");

__device__ __forceinline__ float fexp2(float x) { return __builtin_amdgcn_exp2f(x); }

__device__ __forceinline__ f32x4 mfma16(bf16x8 a, bf16x8 b, f32x4 c) {
    return __builtin_amdgcn_mfma_f32_16x16x32_bf16(a, b, c, 0, 0, 0);
}

// ---------------------------------------------------------------------------
// K0a: Wo [1024(in)][1024(out)] fp32 -> WoT [out][in] bf16. grid (16,16).
// ---------------------------------------------------------------------------
__global__ __launch_bounds__(256) void k_transpose_wo(
    const float* __restrict__ Wo, unsigned short* __restrict__ WoT)
{
    __shared__ float t[64][65];
    const int i0 = blockIdx.x * 64;
    const int o0 = blockIdx.y * 64;
    const int tid = threadIdx.x;
    #pragma unroll
    for (int p = 0; p < 16; ++p) {
        int idx = tid + p * 256;
        int r = idx >> 6, c = idx & 63;
        t[r][c] = Wo[(size_t)(i0 + r) * D_ + o0 + c];
    }
    __syncthreads();
    #pragma unroll
    for (int p = 0; p < 16; ++p) {
        int idx = tid + p * 256;
        int r = idx >> 6, c = idx & 63;
        reinterpret_cast<__bf16*>(WoT)[(size_t)(o0 + r) * D_ + i0 + c] = (__bf16)t[c][r];
    }
}

// ---------------------------------------------------------------------------
// K0b: Wq/Wk/Wv [H][d][e] fp32 -> WT [z][h][e][d] bf16. grid (H,3), block 256.
// ---------------------------------------------------------------------------
__global__ __launch_bounds__(256) void k_transpose_w(
    const float* __restrict__ Wq, const float* __restrict__ Wk,
    const float* __restrict__ Wv, unsigned short* __restrict__ WT)
{
    __shared__ float t[64][65];
    const int h = blockIdx.x, z = blockIdx.y;
    const float* W = (z == 0) ? Wq : (z == 1) ? Wk : Wv;
    const int tid = threadIdx.x;
    #pragma unroll
    for (int p = 0; p < 4; ++p) {
        int idx = tid + p * 256;
        int r = idx >> 4, c4 = (idx & 15) * 4;
        *reinterpret_cast<float4*>(&t[r][c4]) =
            *reinterpret_cast<const float4*>(&W[h * 4096 + r * 64 + c4]);
    }
    __syncthreads();
    const int e = tid >> 2, db = (tid & 3) * 16;
    __bf16* out = reinterpret_cast<__bf16*>(WT) + ((size_t)(z * H_ + h) * 64 + e) * 64 + db;
    #pragma unroll
    for (int jj = 0; jj < 2; ++jj) {
        bf16x8 v;
        #pragma unroll
        for (int j = 0; j < 8; ++j) v[j] = (__bf16)t[db + jj * 8 + j][e];
        *reinterpret_cast<bf16x8*>(out + jj * 8) = v;
    }
}

// ---------------------------------------------------------------------------
// K1 (v4): QKV projection, fused z-loop, MFMA. NEW: LDS-bounce epilogue —
// accumulators go through swizzled Ml so ALL global stores are coalesced
// (128B/256B contiguous per 8/16 lanes) instead of 16x scattered 8B segments.
// grid (TOK/128, H), block 256.
// ---------------------------------------------------------------------------
__global__ __launch_bounds__(256) void k_qkv(
    const float* __restrict__ X, const unsigned short* __restrict__ WT,
    const float* __restrict__ bq, const float* __restrict__ bk,
    const float* __restrict__ bv,
    unsigned short* __restrict__ Qo, unsigned short* __restrict__ Ko,
    unsigned short* __restrict__ Vt)
{
    __shared__ unsigned short Xl[128 * 64];      // 16 KB, swizzled slots
    __shared__ unsigned short Wl[3][64 * 64];    // 24 KB, swizzled slots
    __shared__ unsigned short Ml[128 * 64];      // 16 KB bounce buffer

    const int tid  = threadIdx.x;
    const int lane = tid & 63, w = tid >> 6;
    const int g = lane >> 4, q = lane & 15;
    const int tok0 = blockIdx.x * 128;
    const int h    = blockIdx.y;

    #pragma unroll
    for (int i = 0; i < 4; ++i) {
        int c = tid + 256 * i;
        int row = c >> 3, slot = c & 7;
        const float* src = &X[(size_t)(tok0 + row) * D_ + h * HD_ + slot * 8];
        float4 x0 = *reinterpret_cast<const float4*>(src);
        float4 x1 = *reinterpret_cast<const float4*>(src + 4);
        bf16x8 v = { (__bf16)x0.x, (__bf16)x0.y, (__bf16)x0.z, (__bf16)x0.w,
                     (__bf16)x1.x, (__bf16)x1.y, (__bf16)x1.z, (__bf16)x1.w };
        *reinterpret_cast<bf16x8*>(
            reinterpret_cast<char*>(Xl) + row * 128 + ((slot ^ (row & 7)) * 16)) = v;
    }
    #pragma unroll
    for (int zz = 0; zz < 3; ++zz) {
        #pragma unroll
        for (int i = 0; i < 2; ++i) {
            int c = tid + 256 * i;
            int e = c >> 3, slot = c & 7;
            bf16x8 v = *reinterpret_cast<const bf16x8*>(
                &WT[((size_t)(zz * H_ + h) * 64 + e) * 64 + slot * 8]);
            *reinterpret_cast<bf16x8*>(
                reinterpret_cast<char*>(Wl[zz]) + e * 128 + ((slot ^ (e & 7)) * 16)) = v;
        }
    }
    __syncthreads();

    const float scq = 0.18033688011112042f;  // log2(e)/8
    const int b       = tok0 >> 11;
    const int tokbase = tok0 & (S_ - 1);
    const int sbw     = w * 32;              // wave's token offset in tile

    #pragma unroll
    for (int z = 0; z < 3; ++z) {
        const float* bb = (z == 0) ? bq : (z == 1) ? bk : bv;
        f32x4 acc[2][4] = {};
        #pragma unroll
        for (int s = 0; s < 2; ++s) {
            bf16x8 af[2], bfr[4];
            #pragma unroll
            for (int am = 0; am < 2; ++am) {
                int row  = sbw + am * 16 + q;
                int slot = (s * 4 + g) ^ (row & 7);
                af[am] = *reinterpret_cast<const bf16x8*>(
                    reinterpret_cast<const char*>(Xl) + row * 128 + slot * 16);
            }
            #pragma unroll
            for (int bn = 0; bn < 4; ++bn) {
                int row  = bn * 16 + q;
                int slot = (s * 4 + g) ^ (row & 7);
                bfr[bn] = *reinterpret_cast<const bf16x8*>(
                    reinterpret_cast<const char*>(Wl[z]) + row * 128 + slot * 16);
            }
            if (z == 2) {
                #pragma unroll
                for (int am = 0; am < 2; ++am)
                    #pragma unroll
                    for (int bn = 0; bn < 4; ++bn)
                        acc[am][bn] = mfma16(af[am], bfr[bn], acc[am][bn]);
            } else {
                #pragma unroll
                for (int am = 0; am < 2; ++am)
                    #pragma unroll
                    for (int bn = 0; bn < 4; ++bn)
                        acc[am][bn] = mfma16(bfr[bn], af[am], acc[am][bn]);
            }
        }

        if (z == 2) {
            // ---- V: Ml as [e (64 rows)][tok (128 cols)] bf16, swizzled ----
            // acc[am][bn][j] -> tok = sbw + am*16 + 4g + j, e = bn*16 + q
            #pragma unroll
            for (int bn = 0; bn < 4; ++bn) {
                int e = bn * 16 + q;
                float bia = bb[h * HD_ + e];
                #pragma unroll
                for (int am = 0; am < 2; ++am) {
                    int tokl  = sbw + am * 16 + 4 * g;
                    int chunk = tokl >> 3;
                    bf16x4 ov = { (__bf16)(acc[am][bn][0] + bia), (__bf16)(acc[am][bn][1] + bia),
                                  (__bf16)(acc[am][bn][2] + bia), (__bf16)(acc[am][bn][3] + bia) };
                    *reinterpret_cast<bf16x4*>(
                        reinterpret_cast<char*>(Ml) + e * 256 +
                        ((chunk ^ (e & 15)) * 16) + (g & 1) * 8) = ov;
                }
            }
            __syncthreads();
            #pragma unroll
            for (int p4 = 0; p4 < 4; ++p4) {
                int e = p4 * 16 + (tid >> 4);
                int chunk = tid & 15;
                bf16x8 v = *reinterpret_cast<const bf16x8*>(
                    reinterpret_cast<const char*>(Ml) + e * 256 + ((chunk ^ (e & 15)) * 16));
                *reinterpret_cast<bf16x8*>(
                    &Vt[((size_t)(b * H_ + h) * HD_ + e) * S_ + tokbase + chunk * 8]) = v;
            }
            __syncthreads();
        } else {
            // ---- Q/K: Ml as [tok (128 rows)][e (64 cols)] bf16, swizzled ----
            // acc[am][bn][j] -> e = bn*16 + 4g + j, tok = sbw + am*16 + q
            const float sc = (z == 0) ? scq : 1.0f;
            #pragma unroll
            for (int bn = 0; bn < 4; ++bn) {
                float4 bia4 = *reinterpret_cast<const float4*>(&bb[h * HD_ + bn * 16 + 4 * g]);
                int slot = 2 * bn + (g >> 1);
                #pragma unroll
                for (int am = 0; am < 2; ++am) {
                    int tokl = sbw + am * 16 + q;
                    bf16x4 ov = { (__bf16)((acc[am][bn][0] + bia4.x) * sc),
                                  (__bf16)((acc[am][bn][1] + bia4.y) * sc),
                                  (__bf16)((acc[am][bn][2] + bia4.z) * sc),
                                  (__bf16)((acc[am][bn][3] + bia4.w) * sc) };
                    *reinterpret_cast<bf16x4*>(
                        reinterpret_cast<char*>(Ml) + tokl * 128 +
                        ((slot ^ (tokl & 7)) * 16) + (g & 1) * 8) = ov;
                }
            }
            __syncthreads();
            unsigned short* dst = (z == 0) ? Qo : Ko;
            #pragma unroll
            for (int p4 = 0; p4 < 4; ++p4) {
                int row = p4 * 32 + (tid >> 3);
                int chunk = tid & 7;
                bf16x8 v = *reinterpret_cast<const bf16x8*>(
                    reinterpret_cast<const char*>(Ml) + row * 128 + ((chunk ^ (row & 7)) * 16));
                *reinterpret_cast<bf16x8*>(
                    &dst[((size_t)(b * H_ + h) * S_ + tokbase + row) * HD_ + chunk * 8]) = v;
            }
            __syncthreads();
        }
    }
}

// ---------------------------------------------------------------------------
// K2 (v7): flash attention = v6 (in-reg P via K-row-permuted staging) + 32
// q-rows per wave (dual qset A/B): K/V LDS frag reads amortize over 2x
// queries — the calibrated LDS-throughput bottleneck. 4 waves x 32q = 128
// q/block; grid (16,32)=512 blocks (2/CU, 8 waves/CU). Staging maps are the
// 256-thread FULL-coverage ones (r4/r9-verified). Dbuf, 1 barrier/iter,
// defer-max (T13), setprio (T5), XCD-grouped bh map.
// ---------------------------------------------------------------------------
__global__ __launch_bounds__(256) void k_attn(
    const unsigned short* __restrict__ Q,
    const unsigned short* __restrict__ K,
    const unsigned short* __restrict__ V,
    unsigned short* __restrict__ O)
{
    __shared__ unsigned short K_lds[2][32 * 72];  // permuted rows, +8 pad
    __shared__ unsigned short V_lds[2][64 * 40];  // [dim][key], +8 pad

    const int L  = blockIdx.x + (int)gridDim.x * blockIdx.y;  // 0..511
    const int bh = (L & 7) * 4 + ((L >> 3) & 3);              // XCD-grouped
    const int sb = L >> 5;                                    // q-tile (128 q)

    const unsigned short* Qp = Q + (size_t)bh * S_ * HD_;
    const unsigned short* Kp = K + (size_t)bh * S_ * HD_;
    const unsigned short* Vp = V + (size_t)bh * HD_ * S_;

    const int tid  = threadIdx.x;
    const int lane = tid & 63, w = tid >> 6;      // 4 waves
    const int g = lane >> 4, q = lane & 15;
    const int q0   = sb * 128 + w * 32;
    const int rowA = q0 + q, rowB = q0 + 16 + q;

    bf16x8 qfA0 = *reinterpret_cast<const bf16x8*>(&Qp[(size_t)rowA * HD_ + 8 * g]);
    bf16x8 qfA1 = *reinterpret_cast<const bf16x8*>(&Qp[(size_t)rowA * HD_ + 32 + 8 * g]);
    bf16x8 qfB0 = *reinterpret_cast<const bf16x8*>(&Qp[(size_t)rowB * HD_ + 8 * g]);
    bf16x8 qfB1 = *reinterpret_cast<const bf16x8*>(&Qp[(size_t)rowB * HD_ + 32 + 8 * g]);

    f32x4 accA[4] = {}, accB[4] = {};
    float mA = -3.0e38f, mB = -3.0e38f, lA = 0.0f, lB = 0.0f;

    // staging maps (256 threads, FULL coverage):
    const int kr = tid >> 3, ks = (tid & 7) * 8;
    const int vr = tid >> 2, vs = (tid & 3) * 8;
    const int krp = (kr & 4) ? (16 + 4 * (kr >> 3) + (kr & 3))
                             : (4 * (kr >> 3) + (kr & 3));

    const unsigned short* kSrc = Kp + (size_t)kr * HD_ + ks;
    const unsigned short* vSrc = Vp + (size_t)vr * S_  + vs;

    {
        uint4 k0 = *reinterpret_cast<const uint4*>(kSrc);
        uint4 v0 = *reinterpret_cast<const uint4*>(vSrc);
        *reinterpret_cast<uint4*>(&K_lds[0][krp * 72 + ks]) = k0;
        *reinterpret_cast<uint4*>(&V_lds[0][vr * 40 + vs])  = v0;
    }
    __syncthreads();

    const int NT = S_ / 32;   // 64 tiles
    for (int t = 0; t < NT; ++t) {
        const int cur = t & 1, nxt = cur ^ 1;

        uint4 kn, vn;
        const bool more = (t + 1 < NT);
        if (more) {
            kn = *reinterpret_cast<const uint4*>(kSrc + (size_t)(t + 1) * 32 * HD_);
            vn = *reinterpret_cast<const uint4*>(vSrc + (size_t)(t + 1) * 32);
        }

        const unsigned short* Kb = K_lds[cur];
        const unsigned short* Vb = V_lds[cur];
        bf16x8 k00 = *reinterpret_cast<const bf16x8*>(&Kb[q * 72 + 8 * g]);
        bf16x8 k01 = *reinterpret_cast<const bf16x8*>(&Kb[q * 72 + 32 + 8 * g]);
        bf16x8 k10 = *reinterpret_cast<const bf16x8*>(&Kb[(16 + q) * 72 + 8 * g]);
        bf16x8 k11 = *reinterpret_cast<const bf16x8*>(&Kb[(16 + q) * 72 + 32 + 8 * g]);
        bf16x8 vf0 = *reinterpret_cast<const bf16x8*>(&Vb[(0 * 16 + q) * 40 + 8 * g]);
        bf16x8 vf1 = *reinterpret_cast<const bf16x8*>(&Vb[(1 * 16 + q) * 40 + 8 * g]);
        bf16x8 vf2 = *reinterpret_cast<const bf16x8*>(&Vb[(2 * 16 + q) * 40 + 8 * g]);
        bf16x8 vf3 = *reinterpret_cast<const bf16x8*>(&Vb[(3 * 16 + q) * 40 + 8 * g]);

        // S^T = K.Q^T with permuted A-rows: lane(g,q) gets keys 8g..8g+7.
        f32x4 z4 = {0.f, 0.f, 0.f, 0.f};
        __builtin_amdgcn_s_setprio(1);
        f32x4 sA0 = mfma16(k00, qfA0, z4); sA0 = mfma16(k01, qfA1, sA0);
        f32x4 sA1 = mfma16(k10, qfA0, z4); sA1 = mfma16(k11, qfA1, sA1);
        f32x4 sB0 = mfma16(k00, qfB0, z4); sB0 = mfma16(k01, qfB1, sB0);
        f32x4 sB1 = mfma16(k10, qfB0, z4); sB1 = mfma16(k11, qfB1, sB1);
        __builtin_amdgcn_s_setprio(0);

        // online softmax (dual), defer-max fast path
        float pmA = fmaxf(fmaxf(fmaxf(sA0[0], sA0[1]), fmaxf(sA0[2], sA0[3])),
                          fmaxf(fmaxf(sA1[0], sA1[1]), fmaxf(sA1[2], sA1[3])));
        float pmB = fmaxf(fmaxf(fmaxf(sB0[0], sB0[1]), fmaxf(sB0[2], sB0[3])),
                          fmaxf(fmaxf(sB1[0], sB1[1]), fmaxf(sB1[2], sB1[3])));
        if (!__all((pmA - mA <= 8.0f) && (pmB - mB <= 8.0f))) {
            float rA = pmA;
            rA = fmaxf(rA, __shfl_xor(rA, 16));
            rA = fmaxf(rA, __shfl_xor(rA, 32));
            float mnA = fmaxf(mA, rA);
            float sclA = fexp2(mA - mnA);
            mA = mnA; lA *= sclA;
            accA[0] *= sclA; accA[1] *= sclA; accA[2] *= sclA; accA[3] *= sclA;
            float rB = pmB;
            rB = fmaxf(rB, __shfl_xor(rB, 16));
            rB = fmaxf(rB, __shfl_xor(rB, 32));
            float mnB = fmaxf(mB, rB);
            float sclB = fexp2(mB - mnB);
            mB = mnB; lB *= sclB;
            accB[0] *= sclB; accB[1] *= sclB; accB[2] *= sclB; accB[3] *= sclB;
        }
        float pA0 = fexp2(sA0[0] - mA), pA1 = fexp2(sA0[1] - mA);
        float pA2 = fexp2(sA0[2] - mA), pA3 = fexp2(sA0[3] - mA);
        float pA4 = fexp2(sA1[0] - mA), pA5 = fexp2(sA1[1] - mA);
        float pA6 = fexp2(sA1[2] - mA), pA7 = fexp2(sA1[3] - mA);
        float pB0 = fexp2(sB0[0] - mB), pB1 = fexp2(sB0[1] - mB);
        float pB2 = fexp2(sB0[2] - mB), pB3 = fexp2(sB0[3] - mB);
        float pB4 = fexp2(sB1[0] - mB), pB5 = fexp2(sB1[1] - mB);
        float pB6 = fexp2(sB1[2] - mB), pB7 = fexp2(sB1[3] - mB);
        lA += ((pA0 + pA1) + (pA2 + pA3)) + ((pA4 + pA5) + (pA6 + pA7));
        lB += ((pB0 + pB1) + (pB2 + pB3)) + ((pB4 + pB5) + (pB6 + pB7));

        // P in registers: keys 8g..8g+7 in order = PV B-fragment
        bf16x8 pfA = { (__bf16)pA0, (__bf16)pA1, (__bf16)pA2, (__bf16)pA3,
                       (__bf16)pA4, (__bf16)pA5, (__bf16)pA6, (__bf16)pA7 };
        bf16x8 pfB = { (__bf16)pB0, (__bf16)pB1, (__bf16)pB2, (__bf16)pB3,
                       (__bf16)pB4, (__bf16)pB5, (__bf16)pB6, (__bf16)pB7 };

        __builtin_amdgcn_s_setprio(1);
        accA[0] = mfma16(vf0, pfA, accA[0]);
        accA[1] = mfma16(vf1, pfA, accA[1]);
        accA[2] = mfma16(vf2, pfA, accA[2]);
        accA[3] = mfma16(vf3, pfA, accA[3]);
        accB[0] = mfma16(vf0, pfB, accB[0]);
        accB[1] = mfma16(vf1, pfB, accB[1]);
        accB[2] = mfma16(vf2, pfB, accB[2]);
        accB[3] = mfma16(vf3, pfB, accB[3]);
        __builtin_amdgcn_s_setprio(0);

        if (more) {
            *reinterpret_cast<uint4*>(&K_lds[nxt][krp * 72 + ks]) = kn;
            *reinterpret_cast<uint4*>(&V_lds[nxt][vr * 40 + vs])  = vn;
        }
        __syncthreads();
    }

    // ---- epilogue (dual) ----
    lA += __shfl_xor(lA, 16);  lA += __shfl_xor(lA, 32);
    lB += __shfl_xor(lB, 16);  lB += __shfl_xor(lB, 32);
    const float invA = 1.0f / lA, invB = 1.0f / lB;
    const int b = bh >> 4, h = bh & 15;
    __bf16* Ob = reinterpret_cast<__bf16*>(O);
    size_t rA_ = (size_t)(b * S_ + rowA) * D_ + h * HD_ + 4 * g;
    size_t rB_ = (size_t)(b * S_ + rowB) * D_ + h * HD_ + 4 * g;
    #pragma unroll
    for (int d = 0; d < 4; ++d) {
        bf16x4 oa = { (__bf16)(accA[d][0]*invA), (__bf16)(accA[d][1]*invA),
                      (__bf16)(accA[d][2]*invA), (__bf16)(accA[d][3]*invA) };
        bf16x4 ob = { (__bf16)(accB[d][0]*invB), (__bf16)(accB[d][1]*invB),
                      (__bf16)(accB[d][2]*invB), (__bf16)(accB[d][3]*invB) };
        *reinterpret_cast<bf16x4*>(&Ob[rA_ + 16 * d]) = oa;
        *reinterpret_cast<bf16x4*>(&Ob[rB_ + 16 * d]) = ob;
    }
}

// ---------------------------------------------------------------------------
// K3 (v3, unchanged): out = O_attn(bf16) @ WoT + bo, fp32. 64x64 tile, BK=64,
// dbuf swizzled LDS. grid (64,16), block 256.
// ---------------------------------------------------------------------------
__global__ __launch_bounds__(256) void k_out(
    const unsigned short* __restrict__ A,
    const unsigned short* __restrict__ Wt,
    const float* __restrict__ bo,
    float* __restrict__ C)
{
    __shared__ unsigned short Al[2][64 * 64];
    __shared__ unsigned short Bl[2][64 * 64];

    const int tid  = threadIdx.x;
    const int lane = tid & 63, w = tid >> 6;
    const int g = lane >> 4, q = lane & 15;
    const int wr = w & 1, wc = w >> 1;
    const int m0 = blockIdx.x * 64;
    const int n0 = blockIdx.y * 64;

    int    sbyte[2];
    size_t sgA[2], sgB[2];
    #pragma unroll
    for (int i = 0; i < 2; ++i) {
        int c = tid + 256 * i;
        int row = c >> 3, slot = c & 7;
        sbyte[i] = row * 128 + ((slot ^ (row & 7)) * 16);
        sgA[i] = (size_t)(m0 + row) * D_ + slot * 8;
        sgB[i] = (size_t)(n0 + row) * D_ + slot * 8;
    }

    uint4 ra[2], rb[2];
    #pragma unroll
    for (int i = 0; i < 2; ++i) {
        ra[i] = *reinterpret_cast<const uint4*>(A  + sgA[i]);
        rb[i] = *reinterpret_cast<const uint4*>(Wt + sgB[i]);
    }
    #pragma unroll
    for (int i = 0; i < 2; ++i) {
        *reinterpret_cast<uint4*>(reinterpret_cast<char*>(Al[0]) + sbyte[i]) = ra[i];
        *reinterpret_cast<uint4*>(reinterpret_cast<char*>(Bl[0]) + sbyte[i]) = rb[i];
    }
    __syncthreads();

    f32x4 acc[2][2] = {};
    const int NKT = D_ / 64;   // 16
    for (int kt = 0; kt < NKT; ++kt) {
        const int cur = kt & 1, nxt = cur ^ 1;
        const bool more = (kt + 1 < NKT);
        if (more) {
            #pragma unroll
            for (int i = 0; i < 2; ++i) {
                ra[i] = *reinterpret_cast<const uint4*>(A  + sgA[i] + (kt + 1) * 64);
                rb[i] = *reinterpret_cast<const uint4*>(Wt + sgB[i] + (kt + 1) * 64);
            }
        }
        const char* Ab = reinterpret_cast<const char*>(Al[cur]);
        const char* Bb = reinterpret_cast<const char*>(Bl[cur]);
        #pragma unroll
        for (int s = 0; s < 2; ++s) {
            bf16x8 af[2], bfr[2];
            #pragma unroll
            for (int am = 0; am < 2; ++am) {
                int row  = wr * 32 + am * 16 + q;
                int slot = (s * 4 + g) ^ (row & 7);
                af[am] = *reinterpret_cast<const bf16x8*>(Ab + row * 128 + slot * 16);
            }
            #pragma unroll
            for (int bn = 0; bn < 2; ++bn) {
                int row  = wc * 32 + bn * 16 + q;
                int slot = (s * 4 + g) ^ (row & 7);
                bfr[bn] = *reinterpret_cast<const bf16x8*>(Bb + row * 128 + slot * 16);
            }
            #pragma unroll
            for (int am = 0; am < 2; ++am)
                #pragma unroll
                for (int bn = 0; bn < 2; ++bn)
                    acc[am][bn] = mfma16(af[am], bfr[bn], acc[am][bn]);
        }
        if (more) {
            #pragma unroll
            for (int i = 0; i < 2; ++i) {
                *reinterpret_cast<uint4*>(reinterpret_cast<char*>(Al[nxt]) + sbyte[i]) = ra[i];
                *reinterpret_cast<uint4*>(reinterpret_cast<char*>(Bl[nxt]) + sbyte[i]) = rb[i];
            }
        }
        __syncthreads();
    }

    #pragma unroll
    for (int bn = 0; bn < 2; ++bn) {
        int n = n0 + wc * 32 + bn * 16 + q;
        float bia = bo[n];
        #pragma unroll
        for (int am = 0; am < 2; ++am) {
            int mbase = m0 + wr * 32 + am * 16 + 4 * g;
            #pragma unroll
            for (int j = 0; j < 4; ++j)
                C[(size_t)(mbase + j) * D_ + n] = acc[am][bn][j] + bia;
        }
    }
}

// ---------------------------------------------------------------------------
extern "C" void kernel_launch(void* const* d_in, const int* in_sizes, int n_in,
                              void* d_out, int out_size, void* d_ws, size_t ws_size,
                              hipStream_t stream)
{
    const float* X  = (const float*)d_in[0];
    const float* Wq = (const float*)d_in[1];
    const float* bq = (const float*)d_in[2];
    const float* Wk = (const float*)d_in[3];
    const float* bk = (const float*)d_in[4];
    const float* Wv = (const float*)d_in[5];
    const float* bv = (const float*)d_in[6];
    const float* Wo = (const float*)d_in[7];
    const float* bo = (const float*)d_in[8];
    float* out = (float*)d_out;

    unsigned short* ws = (unsigned short*)d_ws;
    const size_t QN = (size_t)B_ * H_ * S_ * HD_;     // 4M elements
    unsigned short* Qb    = ws;                       // 8 MB
    unsigned short* Kb    = ws + QN;                  // 8 MB
    unsigned short* Vtb   = ws + 2 * QN;              // 8 MB
    unsigned short* Ob    = ws + 3 * QN;              // 8 MB
    unsigned short* WoT   = ws + 4 * QN;              // 2 MB
    unsigned short* WqkvT = ws + 4 * QN + (size_t)D_ * D_;  // 384 KB

    k_transpose_wo<<<dim3(16, 16), 256, 0, stream>>>(Wo, WoT);
    k_transpose_w<<<dim3(H_, 3), 256, 0, stream>>>(Wq, Wk, Wv, WqkvT);
    k_qkv<<<dim3(TOK / 128, H_), 256, 0, stream>>>(X, WqkvT, bq, bk, bv, Qb, Kb, Vtb);
    k_attn<<<dim3(16, 32), 256, 0, stream>>>(Qb, Kb, Vtb, Ob);
    k_out<<<dim3(TOK / 64, D_ / 64), 256, 0, stream>>>(Ob, WoT, bo, out);
}

// Round 11
// 165.176 us; speedup vs baseline: 1.0432x; 1.0432x over previous
//
#include <hip/hip_runtime.h>
#include <stdint.h>

#define B_  2
#define S_  2048
#define D_  1024
#define H_  16
#define HD_ 64
#define TOK (B_*S_)   // 4096

typedef __bf16 bf16x8 __attribute__((ext_vector_type(8)));
typedef __bf16 bf16x4 __attribute__((ext_vector_type(4)));
typedef float  f32x4  __attribute__((ext_vector_type(4)));

static_assert(sizeof(bf16x8) == 16, "bf16x8 must be 16B");
static_assert(sizeof(bf16x4) == 8,  "bf16x4 must be 8B");

__device__ __forceinline__ float fexp2(float x) { return __builtin_amdgcn_exp2f(x); }

__device__ __forceinline__ f32x4 mfma16(bf16x8 a, bf16x8 b, f32x4 c) {
    return __builtin_amdgcn_mfma_f32_16x16x32_bf16(a, b, c, 0, 0, 0);
}

// ---------------------------------------------------------------------------
// K0 (fused prep): one kernel, two jobs.
//   blockIdx.x 0..255  : Wo [1024][1024] fp32 -> WoT [out][in] bf16 (64x64 tile)
//   blockIdx.x 256..303: Wq/Wk/Wv [H][64][64] fp32 -> WT [z][h][e][d] bf16
// block 256.
// ---------------------------------------------------------------------------
__global__ __launch_bounds__(256) void k_prep(
    const float* __restrict__ Wo,
    const float* __restrict__ Wq, const float* __restrict__ Wk,
    const float* __restrict__ Wv,
    unsigned short* __restrict__ WoT, unsigned short* __restrict__ WT)
{
    __shared__ float t[64][65];
    const int bx  = blockIdx.x;
    const int tid = threadIdx.x;

    if (bx < 256) {
        const int i0 = (bx & 15) * 64;
        const int o0 = (bx >> 4) * 64;
        #pragma unroll
        for (int p = 0; p < 16; ++p) {
            int idx = tid + p * 256;
            int r = idx >> 6, c = idx & 63;
            t[r][c] = Wo[(size_t)(i0 + r) * D_ + o0 + c];
        }
        __syncthreads();
        #pragma unroll
        for (int p = 0; p < 16; ++p) {
            int idx = tid + p * 256;
            int r = idx >> 6, c = idx & 63;
            reinterpret_cast<__bf16*>(WoT)[(size_t)(o0 + r) * D_ + i0 + c] = (__bf16)t[c][r];
        }
    } else {
        const int idx0 = bx - 256;          // 0..47
        const int h = idx0 & 15, z = idx0 >> 4;
        const float* W = (z == 0) ? Wq : (z == 1) ? Wk : Wv;
        #pragma unroll
        for (int p = 0; p < 4; ++p) {
            int idx = tid + p * 256;
            int r = idx >> 4, c4 = (idx & 15) * 4;
            *reinterpret_cast<float4*>(&t[r][c4]) =
                *reinterpret_cast<const float4*>(&W[h * 4096 + r * 64 + c4]);
        }
        __syncthreads();
        const int e = tid >> 2, db = (tid & 3) * 16;
        __bf16* out = reinterpret_cast<__bf16*>(WT) + ((size_t)(z * H_ + h) * 64 + e) * 64 + db;
        #pragma unroll
        for (int jj = 0; jj < 2; ++jj) {
            bf16x8 v;
            #pragma unroll
            for (int j = 0; j < 8; ++j) v[j] = (__bf16)t[db + jj * 8 + j][e];
            *reinterpret_cast<bf16x8*>(out + jj * 8) = v;
        }
    }
}

// ---------------------------------------------------------------------------
// K1 (v4, unchanged from r10 — passed): QKV projection, fused z-loop, MFMA,
// LDS-bounce epilogue for fully-coalesced stores. grid (TOK/128, H), block 256.
// ---------------------------------------------------------------------------
__global__ __launch_bounds__(256) void k_qkv(
    const float* __restrict__ X, const unsigned short* __restrict__ WT,
    const float* __restrict__ bq, const float* __restrict__ bk,
    const float* __restrict__ bv,
    unsigned short* __restrict__ Qo, unsigned short* __restrict__ Ko,
    unsigned short* __restrict__ Vt)
{
    __shared__ unsigned short Xl[128 * 64];      // 16 KB, swizzled slots
    __shared__ unsigned short Wl[3][64 * 64];    // 24 KB, swizzled slots
    __shared__ unsigned short Ml[128 * 64];      // 16 KB bounce buffer

    const int tid  = threadIdx.x;
    const int lane = tid & 63, w = tid >> 6;
    const int g = lane >> 4, q = lane & 15;
    const int tok0 = blockIdx.x * 128;
    const int h    = blockIdx.y;

    #pragma unroll
    for (int i = 0; i < 4; ++i) {
        int c = tid + 256 * i;
        int row = c >> 3, slot = c & 7;
        const float* src = &X[(size_t)(tok0 + row) * D_ + h * HD_ + slot * 8];
        float4 x0 = *reinterpret_cast<const float4*>(src);
        float4 x1 = *reinterpret_cast<const float4*>(src + 4);
        bf16x8 v = { (__bf16)x0.x, (__bf16)x0.y, (__bf16)x0.z, (__bf16)x0.w,
                     (__bf16)x1.x, (__bf16)x1.y, (__bf16)x1.z, (__bf16)x1.w };
        *reinterpret_cast<bf16x8*>(
            reinterpret_cast<char*>(Xl) + row * 128 + ((slot ^ (row & 7)) * 16)) = v;
    }
    #pragma unroll
    for (int zz = 0; zz < 3; ++zz) {
        #pragma unroll
        for (int i = 0; i < 2; ++i) {
            int c = tid + 256 * i;
            int e = c >> 3, slot = c & 7;
            bf16x8 v = *reinterpret_cast<const bf16x8*>(
                &WT[((size_t)(zz * H_ + h) * 64 + e) * 64 + slot * 8]);
            *reinterpret_cast<bf16x8*>(
                reinterpret_cast<char*>(Wl[zz]) + e * 128 + ((slot ^ (e & 7)) * 16)) = v;
        }
    }
    __syncthreads();

    const float scq = 0.18033688011112042f;  // log2(e)/8
    const int b       = tok0 >> 11;
    const int tokbase = tok0 & (S_ - 1);
    const int sbw     = w * 32;              // wave's token offset in tile

    #pragma unroll
    for (int z = 0; z < 3; ++z) {
        const float* bb = (z == 0) ? bq : (z == 1) ? bk : bv;
        f32x4 acc[2][4] = {};
        #pragma unroll
        for (int s = 0; s < 2; ++s) {
            bf16x8 af[2], bfr[4];
            #pragma unroll
            for (int am = 0; am < 2; ++am) {
                int row  = sbw + am * 16 + q;
                int slot = (s * 4 + g) ^ (row & 7);
                af[am] = *reinterpret_cast<const bf16x8*>(
                    reinterpret_cast<const char*>(Xl) + row * 128 + slot * 16);
            }
            #pragma unroll
            for (int bn = 0; bn < 4; ++bn) {
                int row  = bn * 16 + q;
                int slot = (s * 4 + g) ^ (row & 7);
                bfr[bn] = *reinterpret_cast<const bf16x8*>(
                    reinterpret_cast<const char*>(Wl[z]) + row * 128 + slot * 16);
            }
            if (z == 2) {
                #pragma unroll
                for (int am = 0; am < 2; ++am)
                    #pragma unroll
                    for (int bn = 0; bn < 4; ++bn)
                        acc[am][bn] = mfma16(af[am], bfr[bn], acc[am][bn]);
            } else {
                #pragma unroll
                for (int am = 0; am < 2; ++am)
                    #pragma unroll
                    for (int bn = 0; bn < 4; ++bn)
                        acc[am][bn] = mfma16(bfr[bn], af[am], acc[am][bn]);
            }
        }

        if (z == 2) {
            // V: Ml as [e (64 rows)][tok (128 cols)] bf16, swizzled
            #pragma unroll
            for (int bn = 0; bn < 4; ++bn) {
                int e = bn * 16 + q;
                float bia = bb[h * HD_ + e];
                #pragma unroll
                for (int am = 0; am < 2; ++am) {
                    int tokl  = sbw + am * 16 + 4 * g;
                    int chunk = tokl >> 3;
                    bf16x4 ov = { (__bf16)(acc[am][bn][0] + bia), (__bf16)(acc[am][bn][1] + bia),
                                  (__bf16)(acc[am][bn][2] + bia), (__bf16)(acc[am][bn][3] + bia) };
                    *reinterpret_cast<bf16x4*>(
                        reinterpret_cast<char*>(Ml) + e * 256 +
                        ((chunk ^ (e & 15)) * 16) + (g & 1) * 8) = ov;
                }
            }
            __syncthreads();
            #pragma unroll
            for (int p4 = 0; p4 < 4; ++p4) {
                int e = p4 * 16 + (tid >> 4);
                int chunk = tid & 15;
                bf16x8 v = *reinterpret_cast<const bf16x8*>(
                    reinterpret_cast<const char*>(Ml) + e * 256 + ((chunk ^ (e & 15)) * 16));
                *reinterpret_cast<bf16x8*>(
                    &Vt[((size_t)(b * H_ + h) * HD_ + e) * S_ + tokbase + chunk * 8]) = v;
            }
            __syncthreads();
        } else {
            // Q/K: Ml as [tok (128 rows)][e (64 cols)] bf16, swizzled
            const float sc = (z == 0) ? scq : 1.0f;
            #pragma unroll
            for (int bn = 0; bn < 4; ++bn) {
                float4 bia4 = *reinterpret_cast<const float4*>(&bb[h * HD_ + bn * 16 + 4 * g]);
                int slot = 2 * bn + (g >> 1);
                #pragma unroll
                for (int am = 0; am < 2; ++am) {
                    int tokl = sbw + am * 16 + q;
                    bf16x4 ov = { (__bf16)((acc[am][bn][0] + bia4.x) * sc),
                                  (__bf16)((acc[am][bn][1] + bia4.y) * sc),
                                  (__bf16)((acc[am][bn][2] + bia4.z) * sc),
                                  (__bf16)((acc[am][bn][3] + bia4.w) * sc) };
                    *reinterpret_cast<bf16x4*>(
                        reinterpret_cast<char*>(Ml) + tokl * 128 +
                        ((slot ^ (tokl & 7)) * 16) + (g & 1) * 8) = ov;
                }
            }
            __syncthreads();
            unsigned short* dst = (z == 0) ? Qo : Ko;
            #pragma unroll
            for (int p4 = 0; p4 < 4; ++p4) {
                int row = p4 * 32 + (tid >> 3);
                int chunk = tid & 7;
                bf16x8 v = *reinterpret_cast<const bf16x8*>(
                    reinterpret_cast<const char*>(Ml) + row * 128 + ((chunk ^ (row & 7)) * 16));
                *reinterpret_cast<bf16x8*>(
                    &dst[((size_t)(b * H_ + h) * S_ + tokbase + row) * HD_ + chunk * 8]) = v;
            }
            __syncthreads();
        }
    }
}

// ---------------------------------------------------------------------------
// K2 (v6, REVERTED to r9's proven 65.6 us version): 256-thr/4-wave/16q
// skeleton + in-reg P via K-row-permuted staging. Dbuf, 1 barrier/iter,
// defer-max (T13), setprio (T5), XCD-grouped bh map. grid (32,32), block 256.
// ---------------------------------------------------------------------------
__global__ __launch_bounds__(256) void k_attn(
    const unsigned short* __restrict__ Q,
    const unsigned short* __restrict__ K,
    const unsigned short* __restrict__ V,
    unsigned short* __restrict__ O)
{
    __shared__ unsigned short K_lds[2][32 * 72];  // permuted rows, +8 pad
    __shared__ unsigned short V_lds[2][64 * 40];  // [dim][key], +8 pad

    const int L  = blockIdx.x + (int)gridDim.x * blockIdx.y;  // 0..1023
    const int bh = (L & 7) * 4 + ((L >> 3) & 3);              // XCD-grouped
    const int sb = L >> 5;                                    // q-tile (64 q)

    const unsigned short* Qp = Q + (size_t)bh * S_ * HD_;
    const unsigned short* Kp = K + (size_t)bh * S_ * HD_;
    const unsigned short* Vp = V + (size_t)bh * HD_ * S_;

    const int tid  = threadIdx.x;
    const int lane = tid & 63, w = tid >> 6;      // 4 waves
    const int g = lane >> 4, q = lane & 15;
    const int q0 = sb * 64 + w * 16;

    bf16x8 qf0 = *reinterpret_cast<const bf16x8*>(&Qp[(size_t)(q0 + q) * HD_ + 8 * g]);
    bf16x8 qf1 = *reinterpret_cast<const bf16x8*>(&Qp[(size_t)(q0 + q) * HD_ + 32 + 8 * g]);

    f32x4 acc0 = {0.f, 0.f, 0.f, 0.f}, acc1 = acc0, acc2 = acc0, acc3 = acc0;
    float m = -3.0e38f, lp = 0.0f;

    const int kr = tid >> 3, ks = (tid & 7) * 8;
    const int vr = tid >> 2, vs = (tid & 3) * 8;
    const int krp = (kr & 4) ? (16 + 4 * (kr >> 3) + (kr & 3))
                             : (4 * (kr >> 3) + (kr & 3));

    const unsigned short* kSrc = Kp + (size_t)kr * HD_ + ks;
    const unsigned short* vSrc = Vp + (size_t)vr * S_  + vs;

    {
        uint4 k0 = *reinterpret_cast<const uint4*>(kSrc);
        uint4 v0 = *reinterpret_cast<const uint4*>(vSrc);
        *reinterpret_cast<uint4*>(&K_lds[0][krp * 72 + ks]) = k0;
        *reinterpret_cast<uint4*>(&V_lds[0][vr * 40 + vs])  = v0;
    }
    __syncthreads();

    const int NT = S_ / 32;   // 64 tiles
    for (int t = 0; t < NT; ++t) {
        const int cur = t & 1, nxt = cur ^ 1;

        uint4 kn, vn;
        const bool more = (t + 1 < NT);
        if (more) {
            kn = *reinterpret_cast<const uint4*>(kSrc + (size_t)(t + 1) * 32 * HD_);
            vn = *reinterpret_cast<const uint4*>(vSrc + (size_t)(t + 1) * 32);
        }

        const unsigned short* Kb = K_lds[cur];
        const unsigned short* Vb = V_lds[cur];
        bf16x8 k00 = *reinterpret_cast<const bf16x8*>(&Kb[q * 72 + 8 * g]);
        bf16x8 k01 = *reinterpret_cast<const bf16x8*>(&Kb[q * 72 + 32 + 8 * g]);
        bf16x8 k10 = *reinterpret_cast<const bf16x8*>(&Kb[(16 + q) * 72 + 8 * g]);
        bf16x8 k11 = *reinterpret_cast<const bf16x8*>(&Kb[(16 + q) * 72 + 32 + 8 * g]);
        bf16x8 vf0 = *reinterpret_cast<const bf16x8*>(&Vb[(0 * 16 + q) * 40 + 8 * g]);
        bf16x8 vf1 = *reinterpret_cast<const bf16x8*>(&Vb[(1 * 16 + q) * 40 + 8 * g]);
        bf16x8 vf2 = *reinterpret_cast<const bf16x8*>(&Vb[(2 * 16 + q) * 40 + 8 * g]);
        bf16x8 vf3 = *reinterpret_cast<const bf16x8*>(&Vb[(3 * 16 + q) * 40 + 8 * g]);

        // S^T = K.Q^T with permuted A-rows: lane(g,q) gets keys 8g..8g+3 (s0)
        // and 8g+4..8g+7 (s1) for query-column q.
        f32x4 z4 = {0.f, 0.f, 0.f, 0.f};
        __builtin_amdgcn_s_setprio(1);
        f32x4 s0 = mfma16(k00, qf0, z4); s0 = mfma16(k01, qf1, s0);
        f32x4 s1 = mfma16(k10, qf0, z4); s1 = mfma16(k11, qf1, s1);
        __builtin_amdgcn_s_setprio(0);

        // online softmax, defer-max fast path
        float pmax = fmaxf(fmaxf(fmaxf(s0[0], s0[1]), fmaxf(s0[2], s0[3])),
                           fmaxf(fmaxf(s1[0], s1[1]), fmaxf(s1[2], s1[3])));
        if (!__all(pmax - m <= 8.0f)) {
            float pm = pmax;
            pm = fmaxf(pm, __shfl_xor(pm, 16));
            pm = fmaxf(pm, __shfl_xor(pm, 32));
            float mn  = fmaxf(m, pm);
            float scl = fexp2(m - mn);
            m = mn;
            lp *= scl;
            acc0 *= scl; acc1 *= scl; acc2 *= scl; acc3 *= scl;
        }
        float p0 = fexp2(s0[0] - m), p1 = fexp2(s0[1] - m);
        float p2 = fexp2(s0[2] - m), p3 = fexp2(s0[3] - m);
        float p4 = fexp2(s1[0] - m), p5 = fexp2(s1[1] - m);
        float p6 = fexp2(s1[2] - m), p7 = fexp2(s1[3] - m);
        lp += ((p0 + p1) + (p2 + p3)) + ((p4 + p5) + (p6 + p7));

        // P entirely in registers: keys 8g..8g+7 in order = PV B-fragment
        bf16x8 pf = { (__bf16)p0, (__bf16)p1, (__bf16)p2, (__bf16)p3,
                      (__bf16)p4, (__bf16)p5, (__bf16)p6, (__bf16)p7 };

        __builtin_amdgcn_s_setprio(1);
        acc0 = mfma16(vf0, pf, acc0);
        acc1 = mfma16(vf1, pf, acc1);
        acc2 = mfma16(vf2, pf, acc2);
        acc3 = mfma16(vf3, pf, acc3);
        __builtin_amdgcn_s_setprio(0);

        if (more) {
            *reinterpret_cast<uint4*>(&K_lds[nxt][krp * 72 + ks]) = kn;
            *reinterpret_cast<uint4*>(&V_lds[nxt][vr * 40 + vs])  = vn;
        }
        __syncthreads();
    }

    // ---- epilogue: reduce l over g, write O ----
    lp += __shfl_xor(lp, 16);
    lp += __shfl_xor(lp, 32);
    const float inv = 1.0f / lp;
    const int b = bh >> 4, h = bh & 15;
    __bf16* Ob = reinterpret_cast<__bf16*>(O);
    size_t row = (size_t)(b * S_ + q0 + q) * D_ + h * HD_ + 4 * g;
    bf16x4 o0 = { (__bf16)(acc0[0]*inv), (__bf16)(acc0[1]*inv),
                  (__bf16)(acc0[2]*inv), (__bf16)(acc0[3]*inv) };
    bf16x4 o1 = { (__bf16)(acc1[0]*inv), (__bf16)(acc1[1]*inv),
                  (__bf16)(acc1[2]*inv), (__bf16)(acc1[3]*inv) };
    bf16x4 o2 = { (__bf16)(acc2[0]*inv), (__bf16)(acc2[1]*inv),
                  (__bf16)(acc2[2]*inv), (__bf16)(acc2[3]*inv) };
    bf16x4 o3 = { (__bf16)(acc3[0]*inv), (__bf16)(acc3[1]*inv),
                  (__bf16)(acc3[2]*inv), (__bf16)(acc3[3]*inv) };
    *reinterpret_cast<bf16x4*>(&Ob[row + 0])  = o0;
    *reinterpret_cast<bf16x4*>(&Ob[row + 16]) = o1;
    *reinterpret_cast<bf16x4*>(&Ob[row + 32]) = o2;
    *reinterpret_cast<bf16x4*>(&Ob[row + 48]) = o3;
}

// ---------------------------------------------------------------------------
// K3 (v3, unchanged): out = O_attn(bf16) @ WoT + bo, fp32. 64x64 tile, BK=64,
// dbuf swizzled LDS. grid (64,16), block 256.
// ---------------------------------------------------------------------------
__global__ __launch_bounds__(256) void k_out(
    const unsigned short* __restrict__ A,
    const unsigned short* __restrict__ Wt,
    const float* __restrict__ bo,
    float* __restrict__ C)
{
    __shared__ unsigned short Al[2][64 * 64];
    __shared__ unsigned short Bl[2][64 * 64];

    const int tid  = threadIdx.x;
    const int lane = tid & 63, w = tid >> 6;
    const int g = lane >> 4, q = lane & 15;
    const int wr = w & 1, wc = w >> 1;
    const int m0 = blockIdx.x * 64;
    const int n0 = blockIdx.y * 64;

    int    sbyte[2];
    size_t sgA[2], sgB[2];
    #pragma unroll
    for (int i = 0; i < 2; ++i) {
        int c = tid + 256 * i;
        int row = c >> 3, slot = c & 7;
        sbyte[i] = row * 128 + ((slot ^ (row & 7)) * 16);
        sgA[i] = (size_t)(m0 + row) * D_ + slot * 8;
        sgB[i] = (size_t)(n0 + row) * D_ + slot * 8;
    }

    uint4 ra[2], rb[2];
    #pragma unroll
    for (int i = 0; i < 2; ++i) {
        ra[i] = *reinterpret_cast<const uint4*>(A  + sgA[i]);
        rb[i] = *reinterpret_cast<const uint4*>(Wt + sgB[i]);
    }
    #pragma unroll
    for (int i = 0; i < 2; ++i) {
        *reinterpret_cast<uint4*>(reinterpret_cast<char*>(Al[0]) + sbyte[i]) = ra[i];
        *reinterpret_cast<uint4*>(reinterpret_cast<char*>(Bl[0]) + sbyte[i]) = rb[i];
    }
    __syncthreads();

    f32x4 acc[2][2] = {};
    const int NKT = D_ / 64;   // 16
    for (int kt = 0; kt < NKT; ++kt) {
        const int cur = kt & 1, nxt = cur ^ 1;
        const bool more = (kt + 1 < NKT);
        if (more) {
            #pragma unroll
            for (int i = 0; i < 2; ++i) {
                ra[i] = *reinterpret_cast<const uint4*>(A  + sgA[i] + (kt + 1) * 64);
                rb[i] = *reinterpret_cast<const uint4*>(Wt + sgB[i] + (kt + 1) * 64);
            }
        }
        const char* Ab = reinterpret_cast<const char*>(Al[cur]);
        const char* Bb = reinterpret_cast<const char*>(Bl[cur]);
        #pragma unroll
        for (int s = 0; s < 2; ++s) {
            bf16x8 af[2], bfr[2];
            #pragma unroll
            for (int am = 0; am < 2; ++am) {
                int row  = wr * 32 + am * 16 + q;
                int slot = (s * 4 + g) ^ (row & 7);
                af[am] = *reinterpret_cast<const bf16x8*>(Ab + row * 128 + slot * 16);
            }
            #pragma unroll
            for (int bn = 0; bn < 2; ++bn) {
                int row  = wc * 32 + bn * 16 + q;
                int slot = (s * 4 + g) ^ (row & 7);
                bfr[bn] = *reinterpret_cast<const bf16x8*>(Bb + row * 128 + slot * 16);
            }
            #pragma unroll
            for (int am = 0; am < 2; ++am)
                #pragma unroll
                for (int bn = 0; bn < 2; ++bn)
                    acc[am][bn] = mfma16(af[am], bfr[bn], acc[am][bn]);
        }
        if (more) {
            #pragma unroll
            for (int i = 0; i < 2; ++i) {
                *reinterpret_cast<uint4*>(reinterpret_cast<char*>(Al[nxt]) + sbyte[i]) = ra[i];
                *reinterpret_cast<uint4*>(reinterpret_cast<char*>(Bl[nxt]) + sbyte[i]) = rb[i];
            }
        }
        __syncthreads();
    }

    #pragma unroll
    for (int bn = 0; bn < 2; ++bn) {
        int n = n0 + wc * 32 + bn * 16 + q;
        float bia = bo[n];
        #pragma unroll
        for (int am = 0; am < 2; ++am) {
            int mbase = m0 + wr * 32 + am * 16 + 4 * g;
            #pragma unroll
            for (int j = 0; j < 4; ++j)
                C[(size_t)(mbase + j) * D_ + n] = acc[am][bn][j] + bia;
        }
    }
}

// ---------------------------------------------------------------------------
extern "C" void kernel_launch(void* const* d_in, const int* in_sizes, int n_in,
                              void* d_out, int out_size, void* d_ws, size_t ws_size,
                              hipStream_t stream)
{
    const float* X  = (const float*)d_in[0];
    const float* Wq = (const float*)d_in[1];
    const float* bq = (const float*)d_in[2];
    const float* Wk = (const float*)d_in[3];
    const float* bk = (const float*)d_in[4];
    const float* Wv = (const float*)d_in[5];
    const float* bv = (const float*)d_in[6];
    const float* Wo = (const float*)d_in[7];
    const float* bo = (const float*)d_in[8];
    float* out = (float*)d_out;

    unsigned short* ws = (unsigned short*)d_ws;
    const size_t QN = (size_t)B_ * H_ * S_ * HD_;     // 4M elements
    unsigned short* Qb    = ws;                       // 8 MB
    unsigned short* Kb    = ws + QN;                  // 8 MB
    unsigned short* Vtb   = ws + 2 * QN;              // 8 MB
    unsigned short* Ob    = ws + 3 * QN;              // 8 MB
    unsigned short* WoT   = ws + 4 * QN;              // 2 MB
    unsigned short* WqkvT = ws + 4 * QN + (size_t)D_ * D_;  // 384 KB

    k_prep<<<dim3(304), 256, 0, stream>>>(Wo, Wq, Wk, Wv, WoT, WqkvT);
    k_qkv<<<dim3(TOK / 128, H_), 256, 0, stream>>>(X, WqkvT, bq, bk, bv, Qb, Kb, Vtb);
    k_attn<<<dim3(32, 32), 256, 0, stream>>>(Qb, Kb, Vtb, Ob);
    k_out<<<dim3(TOK / 64, D_ / 64), 256, 0, stream>>>(Ob, WoT, bo, out);
}